// Round 1
// baseline (139.237 us; speedup 1.0000x reference)
//
#include <hip/hip_runtime.h>

// Conv2d as implicit GEMM, bf16 MFMA.
// x: [32,128,56,56] f32, w: [256,128,3,3] f32 -> out: [32,256,56,56] f32
// GEMM view: M=100352 (b*h*w), N=256 (co), K=1152 ordered k=(kh*3+kw)*128+ci.

#define CIN   128
#define HW_   56
#define CO_   256
#define KSZ   1152
#define IMGHW 3136      // 56*56
#define BM    64        // divides 3136 -> block never crosses an image row-space
#define BK    32
#define NSTEP 36        // 1152/32
#define LDSP  40        // BK + 8 ushort pad (80B rows, 16B-aligned, ~2-way banks)

typedef __attribute__((ext_vector_type(8))) __bf16 bf16x8;
typedef __attribute__((ext_vector_type(4))) float f32x4;
typedef __attribute__((ext_vector_type(8))) unsigned short ushort8;

__device__ __forceinline__ unsigned short f2bf(float f) {
    unsigned int u = __float_as_uint(f);
    u += 0x7fffu + ((u >> 16) & 1u);   // RNE
    return (unsigned short)(u >> 16);
}

// Pack weight [co][ci][kh][kw] f32 -> [co][k] bf16 with k=(kh*3+kw)*128+ci.
__global__ void pack_weight(const float* __restrict__ w,
                            unsigned short* __restrict__ wp) {
    int idx = blockIdx.x * 256 + threadIdx.x;     // 256*1152 = 294912 total
    int co = idx / KSZ;
    int k  = idx - co * KSZ;
    int khkw = k >> 7;
    int ci = k & 127;
    wp[idx] = f2bf(w[(co * CIN + ci) * 9 + khkw]);
}

template<bool PACKED>
__global__ __launch_bounds__(256, 2)
void conv_mfma(const float* __restrict__ x,
               const float* __restrict__ wraw,
               const unsigned short* __restrict__ wp,
               float* __restrict__ out)
{
    __shared__ __align__(16) unsigned short Al[2][BM][LDSP];   // im2col rows [m][k]
    __shared__ __align__(16) unsigned short Bl[2][CO_][LDSP];  // weight rows [co][k]

    const int tid  = threadIdx.x;
    const int lane = tid & 63;
    const int wid  = tid >> 6;

    const int mb    = blockIdx.x;          // 1568 blocks
    const int n_img = mb / 49;
    const int hw0   = (mb - n_img * 49) * BM;

    // A staging: thread = (mm = lane, k-slice = wid*8 .. +8)
    const int mm = lane;
    const int hw = hw0 + mm;
    const int h  = hw / HW_;
    const int w_ = hw - h * HW_;

    // B staging: thread = (co = r*64 + tid>>2, k-slice = (tid&3)*8)
    const int bco  = tid >> 2;
    const int bkkg = tid & 3;

    float   aPF[8];
    ushort8 bPF[4];

    auto loadA = [&](int step) {
        int khkw = step >> 2;
        int kh = khkw / 3, kw = khkw - (khkw / 3) * 3;
        int ci0 = (step & 3) * BK + wid * 8;
        int ih = h + kh - 1, iw = w_ + kw - 1;
        bool valid = ((unsigned)ih < (unsigned)HW_) && ((unsigned)iw < (unsigned)HW_);
        const float* px = x + (((size_t)(n_img * CIN + ci0) * HW_ + ih) * HW_ + iw);
        #pragma unroll
        for (int e = 0; e < 8; ++e)
            aPF[e] = valid ? px[e * IMGHW] : 0.f;
    };
    auto writeA = [&](int buf) {
        ushort8 v;
        #pragma unroll
        for (int e = 0; e < 8; ++e) v[e] = f2bf(aPF[e]);
        *(ushort8*)&Al[buf][mm][wid * 8] = v;
    };
    auto loadB = [&](int step) {
        if (PACKED) {
            int k0 = step * BK;
            #pragma unroll
            for (int r = 0; r < 4; ++r)
                bPF[r] = *(const ushort8*)&wp[(r * 64 + bco) * KSZ + k0 + bkkg * 8];
        } else {
            int khkw = step >> 2;
            int ci0 = (step & 3) * BK + bkkg * 8;
            #pragma unroll
            for (int r = 0; r < 4; ++r) {
                int co = r * 64 + bco;
                ushort8 v;
                #pragma unroll
                for (int e = 0; e < 8; ++e)
                    v[e] = f2bf(wraw[(co * CIN + ci0 + e) * 9 + khkw]);
                bPF[r] = v;
            }
        }
    };
    auto writeB = [&](int buf) {
        #pragma unroll
        for (int r = 0; r < 4; ++r)
            *(ushort8*)&Bl[buf][r * 64 + bco][bkkg * 8] = bPF[r];
    };

    f32x4 acc[4][4];
    #pragma unroll
    for (int i = 0; i < 4; ++i)
        #pragma unroll
        for (int j = 0; j < 4; ++j)
            acc[i][j] = (f32x4){0.f, 0.f, 0.f, 0.f};

    const int frow = lane & 15;
    const int fk   = (lane >> 4) * 8;

    loadA(0); loadB(0);
    writeA(0); writeB(0);
    __syncthreads();

    for (int s = 0; s < NSTEP; ++s) {
        const int cur = s & 1;
        if (s + 1 < NSTEP) { loadA(s + 1); loadB(s + 1); }   // prefetch to regs

        ushort8 aF[4], bF[4];
        #pragma unroll
        for (int i = 0; i < 4; ++i)   // A-operand: weight rows (co)
            aF[i] = *(const ushort8*)&Bl[cur][wid * 64 + i * 16 + frow][fk];
        #pragma unroll
        for (int j = 0; j < 4; ++j)   // B-operand: im2col rows (m)
            bF[j] = *(const ushort8*)&Al[cur][j * 16 + frow][fk];

        #pragma unroll
        for (int i = 0; i < 4; ++i)
            #pragma unroll
            for (int j = 0; j < 4; ++j)
                acc[i][j] = __builtin_amdgcn_mfma_f32_16x16x32_bf16(
                    __builtin_bit_cast(bf16x8, aF[i]),
                    __builtin_bit_cast(bf16x8, bF[j]),
                    acc[i][j], 0, 0, 0);

        if (s + 1 < NSTEP) { writeA(cur ^ 1); writeB(cur ^ 1); }
        __syncthreads();
    }

    // Epilogue: D[row=co][col=m]; col = lane&15 -> lanes contiguous in w (coalesced).
    float* ob = out + (size_t)n_img * (CO_ * IMGHW) + hw0;
    #pragma unroll
    for (int i = 0; i < 4; ++i) {
        int co0 = wid * 64 + i * 16 + (lane >> 4) * 4;
        #pragma unroll
        for (int j = 0; j < 4; ++j) {
            int mcol = j * 16 + (lane & 15);
            #pragma unroll
            for (int q = 0; q < 4; ++q)
                ob[(size_t)(co0 + q) * IMGHW + mcol] = acc[i][j][q];
        }
    }
}

extern "C" void kernel_launch(void* const* d_in, const int* in_sizes, int n_in,
                              void* d_out, int out_size, void* d_ws, size_t ws_size,
                              hipStream_t stream) {
    (void)in_sizes; (void)n_in; (void)out_size;
    const float* x  = (const float*)d_in[0];
    const float* wt = (const float*)d_in[1];
    float* out = (float*)d_out;

    const size_t packed_bytes = (size_t)CO_ * KSZ * sizeof(unsigned short); // 590 KB
    const int grid = (CIN * HW_ * HW_ * 32) / (BM * 56 * 56) * 49 / 49;     // = M/BM
    (void)grid;

    if (ws_size >= packed_bytes) {
        unsigned short* wpk = (unsigned short*)d_ws;
        pack_weight<<<(CO_ * KSZ) / 256, 256, 0, stream>>>(wt, wpk);
        conv_mfma<true><<<100352 / BM, 256, 0, stream>>>(x, wt, wpk, out);
    } else {
        conv_mfma<false><<<100352 / BM, 256, 0, stream>>>(x, wt, nullptr, out);
    }
}

// Round 2
// 116.736 us; speedup vs baseline: 1.1928x; 1.1928x over previous
//
#include <hip/hip_runtime.h>
#include <stdint.h>

// Conv2d as implicit GEMM, bf16 MFMA, NHWC-padded-bf16 pre-transform.
// x: [32,128,56,56] f32, w: [256,128,3,3] f32 -> out: [32,256,56,56] f32
// GEMM: M=100352, N=256, K=1152 (k = (kh*3+kw)*128 + ci).

#define CIN   128
#define HW_   56
#define CO_   256
#define KSZ   1152
#define IMGHW 3136
#define HP    58
#define XT_BYTES ((size_t)32 * HP * HP * CIN * 2)   // 27,557,888
#define WP_BYTES ((size_t)CO_ * KSZ * 2)            // 589,824
#define WS_NEED  (XT_BYTES + WP_BYTES)

typedef __attribute__((ext_vector_type(8))) __bf16 bf16x8;
typedef __attribute__((ext_vector_type(4))) float f32x4;
typedef __attribute__((ext_vector_type(8))) unsigned short ushort8;

__device__ __forceinline__ unsigned short f2bf(float f) {
    unsigned int u = __float_as_uint(f);
    u += 0x7fffu + ((u >> 16) & 1u);   // RNE
    return (unsigned short)(u >> 16);
}

__device__ __forceinline__ void gl2lds16(const void* g, void* l) {
    __builtin_amdgcn_global_load_lds(
        (const __attribute__((address_space(1))) void*)g,
        (__attribute__((address_space(3))) void*)l, 16, 0, 0);
}

// ---- weight pack: [co][ci][kh][kw] f32 -> [co][k] bf16, k=(kh*3+kw)*128+ci
__global__ void pack_weight(const float* __restrict__ w,
                            unsigned short* __restrict__ wp) {
    int idx = blockIdx.x * 256 + threadIdx.x;
    int co = idx / KSZ;
    int k  = idx - co * KSZ;
    int khkw = k >> 7;
    int ci = k & 127;
    wp[idx] = f2bf(w[(co * CIN + ci) * 9 + khkw]);
}

// ---- x transform: NCHW f32 -> padded NHWC bf16 [32][58][58][128]
__global__ __launch_bounds__(256)
void xform(const float* __restrict__ x, unsigned short* __restrict__ xt) {
    const int nb = blockIdx.x;          // 32*58
    const int n  = nb / HP;
    const int hp = nb - n * HP;
    unsigned short* orow = xt + ((size_t)n * HP + hp) * (HP * CIN);
    const int t = threadIdx.x;

    if (hp == 0 || hp == HP - 1) {      // border row: zeros (58*128 = 7424 ushorts)
        for (int i = t; i < (HP * CIN) / 8; i += 256)
            ((ushort8*)orow)[i] = (ushort8){0, 0, 0, 0, 0, 0, 0, 0};
        return;
    }
    const int h = hp - 1;
    __shared__ unsigned short T[CIN][HP];      // [ci][w], stride 58 -> conflict-free col reads
    const int wl = t & 63, cg = t >> 6;        // 4 ci rows per iter
    for (int c0 = 0; c0 < CIN; c0 += 4) {
        int ci = c0 + cg;
        if (wl < HW_)
            T[ci][wl] = f2bf(x[(((size_t)n * CIN + ci) * HW_ + h) * HW_ + wl]);
    }
    __syncthreads();
    const int ci = t & 127, wo = t >> 7;       // 2 wp per iter
    for (int wp_ = wo; wp_ < HP; wp_ += 2) {
        unsigned short v = 0;
        if (wp_ >= 1 && wp_ <= HW_) v = T[ci][wp_ - 1];
        orow[wp_ * CIN + ci] = v;
    }
}

// ---- main conv: BM=64, BN=256, BK=32, 256 thr (4 waves), wave tile 64x64
__global__ __launch_bounds__(256, 3)
void conv_main(const unsigned short* __restrict__ xt,
               const unsigned short* __restrict__ wpk,
               float* __restrict__ out)
{
    __shared__ __align__(16) unsigned short Al[2][64][32];    // 8 KB  [m][k]
    __shared__ __align__(16) unsigned short Bl[2][256][32];   // 32 KB [co][k]

    const int tid  = threadIdx.x;
    const int lane = tid & 63;
    const int wv   = tid >> 6;

    int bid = blockIdx.x;
    bid = (bid & 7) * 196 + (bid >> 3);        // XCD swizzle (1568 = 8*196, bijective)
    const int n_img = bid / 49;
    const int hw0   = (bid - n_img * 49) * 64; // 64 | 3136 -> block stays in one image

    // --- staging addresses (fixed per thread) ---
    // chunk swizzle: LDS chunk cb holds logical chunk cb ^ (row&3); row&3 == (lane>>2)&3
    const int cswz = ((lane & 3) ^ ((lane >> 2) & 3)) * 16;

    const int arow = wv * 16 + (lane >> 2);
    const int ah   = (hw0 + arow) / HW_;
    const int aw   = (hw0 + arow) - ah * HW_;
    const char* a_base = (const char*)xt
        + (((size_t)n_img * HP + ah) * HP + aw) * (CIN * 2) + cswz;

    const char* b_base[4];
    #pragma unroll
    for (int j = 0; j < 4; ++j) {
        int brow = (j * 4 + wv) * 16 + (lane >> 2);
        b_base[j] = (const char*)wpk + (size_t)brow * (KSZ * 2) + cswz;
    }

    // --- fragment read offsets (row&3 == lane&3) ---
    const int fswz = (((lane >> 4) ^ (lane & 3)) * 16);
    int off_a[4], off_b[4];
    #pragma unroll
    for (int j = 0; j < 4; ++j) off_a[j] = (j * 16 + (lane & 15)) * 64 + fswz;
    #pragma unroll
    for (int i = 0; i < 4; ++i) off_b[i] = (wv * 64 + i * 16 + (lane & 15)) * 64 + fswz;

    f32x4 acc[4][4];
    #pragma unroll
    for (int i = 0; i < 4; ++i)
        #pragma unroll
        for (int j = 0; j < 4; ++j)
            acc[i][j] = (f32x4){0.f, 0.f, 0.f, 0.f};

    auto stage = [&](int s, int buf) {
        int khkw = s >> 2;
        int kh = khkw / 3, kw = khkw - kh * 3;
        int aoff = (kh * HP + kw) * (CIN * 2) + (s & 3) * 64;
        gl2lds16(a_base + aoff, &Al[buf][wv * 16][0]);
        int boff = s * 64;
        #pragma unroll
        for (int j = 0; j < 4; ++j)
            gl2lds16(b_base[j] + boff, &Bl[buf][(j * 4 + wv) * 16][0]);
    };

    stage(0, 0);
    __syncthreads();

    for (int s = 0; s < 36; ++s) {
        const int cur = s & 1;
        if (s < 35) stage(s + 1, cur ^ 1);

        ushort8 af[4], bf[4];
        const char* Ab = (const char*)&Al[cur][0][0];
        const char* Bb = (const char*)&Bl[cur][0][0];
        #pragma unroll
        for (int j = 0; j < 4; ++j) af[j] = *(const ushort8*)(Ab + off_a[j]);
        #pragma unroll
        for (int i = 0; i < 4; ++i) bf[i] = *(const ushort8*)(Bb + off_b[i]);

        #pragma unroll
        for (int i = 0; i < 4; ++i)
            #pragma unroll
            for (int j = 0; j < 4; ++j)
                acc[i][j] = __builtin_amdgcn_mfma_f32_16x16x32_bf16(
                    __builtin_bit_cast(bf16x8, bf[i]),
                    __builtin_bit_cast(bf16x8, af[j]),
                    acc[i][j], 0, 0, 0);

        __syncthreads();
    }

    // D row = co, col = m (verified layout; same as R1 epilogue)
    float* ob = out + (size_t)n_img * (CO_ * IMGHW) + hw0;
    #pragma unroll
    for (int i = 0; i < 4; ++i) {
        int co0 = wv * 64 + i * 16 + (lane >> 4) * 4;
        #pragma unroll
        for (int j = 0; j < 4; ++j) {
            int mcol = j * 16 + (lane & 15);
            #pragma unroll
            for (int q = 0; q < 4; ++q)
                ob[(size_t)(co0 + q) * IMGHW + mcol] = acc[i][j][q];
        }
    }
}

// ================= fallback (round-1 kernel, used if ws too small) ==========
#define BM    64
#define BK    32
#define NSTEP 36
#define LDSP  40

template<bool PACKED>
__global__ __launch_bounds__(256, 2)
void conv_fb(const float* __restrict__ x,
             const float* __restrict__ wraw,
             const unsigned short* __restrict__ wp,
             float* __restrict__ out)
{
    __shared__ __align__(16) unsigned short Al[2][BM][LDSP];
    __shared__ __align__(16) unsigned short Bl[2][CO_][LDSP];

    const int tid  = threadIdx.x;
    const int lane = tid & 63;
    const int wid  = tid >> 6;

    const int mb    = blockIdx.x;
    const int n_img = mb / 49;
    const int hw0   = (mb - n_img * 49) * BM;

    const int mm = lane;
    const int hw = hw0 + mm;
    const int h  = hw / HW_;
    const int w_ = hw - h * HW_;

    const int bco  = tid >> 2;
    const int bkkg = tid & 3;

    float   aPF[8];
    ushort8 bPF[4];

    auto loadA = [&](int step) {
        int khkw = step >> 2;
        int kh = khkw / 3, kw = khkw - (khkw / 3) * 3;
        int ci0 = (step & 3) * BK + wid * 8;
        int ih = h + kh - 1, iw = w_ + kw - 1;
        bool valid = ((unsigned)ih < (unsigned)HW_) && ((unsigned)iw < (unsigned)HW_);
        const float* px = x + (((size_t)(n_img * CIN + ci0) * HW_ + ih) * HW_ + iw);
        #pragma unroll
        for (int e = 0; e < 8; ++e)
            aPF[e] = valid ? px[e * IMGHW] : 0.f;
    };
    auto writeA = [&](int buf) {
        ushort8 v;
        #pragma unroll
        for (int e = 0; e < 8; ++e) v[e] = f2bf(aPF[e]);
        *(ushort8*)&Al[buf][mm][wid * 8] = v;
    };
    auto loadB = [&](int step) {
        if (PACKED) {
            int k0 = step * BK;
            #pragma unroll
            for (int r = 0; r < 4; ++r)
                bPF[r] = *(const ushort8*)&wp[(r * 64 + bco) * KSZ + k0 + bkkg * 8];
        } else {
            int khkw = step >> 2;
            int ci0 = (step & 3) * BK + bkkg * 8;
            #pragma unroll
            for (int r = 0; r < 4; ++r) {
                int co = r * 64 + bco;
                ushort8 v;
                #pragma unroll
                for (int e = 0; e < 8; ++e)
                    v[e] = f2bf(wraw[(co * CIN + ci0 + e) * 9 + khkw]);
                bPF[r] = v;
            }
        }
    };
    auto writeB = [&](int buf) {
        #pragma unroll
        for (int r = 0; r < 4; ++r)
            *(ushort8*)&Bl[buf][r * 64 + bco][bkkg * 8] = bPF[r];
    };

    f32x4 acc[4][4];
    #pragma unroll
    for (int i = 0; i < 4; ++i)
        #pragma unroll
        for (int j = 0; j < 4; ++j)
            acc[i][j] = (f32x4){0.f, 0.f, 0.f, 0.f};

    const int frow = lane & 15;
    const int fk   = (lane >> 4) * 8;

    loadA(0); loadB(0);
    writeA(0); writeB(0);
    __syncthreads();

    for (int s = 0; s < NSTEP; ++s) {
        const int cur = s & 1;
        if (s + 1 < NSTEP) { loadA(s + 1); loadB(s + 1); }

        ushort8 aF[4], bF[4];
        #pragma unroll
        for (int i = 0; i < 4; ++i)
            aF[i] = *(const ushort8*)&Bl[cur][wid * 64 + i * 16 + frow][fk];
        #pragma unroll
        for (int j = 0; j < 4; ++j)
            bF[j] = *(const ushort8*)&Al[cur][j * 16 + frow][fk];

        #pragma unroll
        for (int i = 0; i < 4; ++i)
            #pragma unroll
            for (int j = 0; j < 4; ++j)
                acc[i][j] = __builtin_amdgcn_mfma_f32_16x16x32_bf16(
                    __builtin_bit_cast(bf16x8, aF[i]),
                    __builtin_bit_cast(bf16x8, bF[j]),
                    acc[i][j], 0, 0, 0);

        if (s + 1 < NSTEP) { writeA(cur ^ 1); writeB(cur ^ 1); }
        __syncthreads();
    }

    float* ob = out + (size_t)n_img * (CO_ * IMGHW) + hw0;
    #pragma unroll
    for (int i = 0; i < 4; ++i) {
        int co0 = wid * 64 + i * 16 + (lane >> 4) * 4;
        #pragma unroll
        for (int j = 0; j < 4; ++j) {
            int mcol = j * 16 + (lane & 15);
            #pragma unroll
            for (int q = 0; q < 4; ++q)
                ob[(size_t)(co0 + q) * IMGHW + mcol] = acc[i][j][q];
        }
    }
}

extern "C" void kernel_launch(void* const* d_in, const int* in_sizes, int n_in,
                              void* d_out, int out_size, void* d_ws, size_t ws_size,
                              hipStream_t stream) {
    (void)in_sizes; (void)n_in; (void)out_size;
    const float* x  = (const float*)d_in[0];
    const float* wt = (const float*)d_in[1];
    float* out = (float*)d_out;

    if (ws_size >= WS_NEED) {
        unsigned short* xt  = (unsigned short*)d_ws;
        unsigned short* wpk = (unsigned short*)((char*)d_ws + XT_BYTES);
        xform<<<32 * HP, 256, 0, stream>>>(x, xt);
        pack_weight<<<(CO_ * KSZ) / 256, 256, 0, stream>>>(wt, wpk);
        conv_main<<<1568, 256, 0, stream>>>(xt, wpk, out);
    } else if (ws_size >= WP_BYTES) {
        unsigned short* wpk = (unsigned short*)d_ws;
        pack_weight<<<(CO_ * KSZ) / 256, 256, 0, stream>>>(wt, wpk);
        conv_fb<true><<<100352 / BM, 256, 0, stream>>>(x, wt, wpk, out);
    } else {
        conv_fb<false><<<100352 / BM, 256, 0, stream>>>(x, wt, nullptr, out);
    }
}

// Round 3
// 98.768 us; speedup vs baseline: 1.4097x; 1.1819x over previous
//
#include <hip/hip_runtime.h>
#include <stdint.h>

// Conv2d as implicit GEMM, bf16 MFMA, 8-phase 256x256 schedule (m201 template).
// x: [32,128,56,56] f32, w: [256,128,3,3] f32 -> out: [32,256,56,56] f32
// GEMM: M=100352, N=256, K=1152 (k = (kh*3+kw)*128 + ci). 18 K-tiles of 64.

#define CIN   128
#define HW_   56
#define CO_   256
#define KSZ   1152
#define IMGHW 3136
#define HP    58
#define NT    18
#define XT_BYTES ((size_t)32 * HP * HP * CIN * 2)   // 27,557,888
#define WP_BYTES ((size_t)CO_ * KSZ * 2)            // 589,824
#define WS_NEED  (XT_BYTES + WP_BYTES)

typedef __attribute__((ext_vector_type(8))) __bf16 bf16x8;
typedef __attribute__((ext_vector_type(4))) float f32x4;
typedef __attribute__((ext_vector_type(8))) unsigned short ushort8;

__device__ __forceinline__ unsigned short f2bf(float f) {
    unsigned int u = __float_as_uint(f);
    u += 0x7fffu + ((u >> 16) & 1u);   // RNE
    return (unsigned short)(u >> 16);
}

__device__ __forceinline__ void gl2lds16(const void* g, void* l) {
    __builtin_amdgcn_global_load_lds(
        (const __attribute__((address_space(1))) void*)g,
        (__attribute__((address_space(3))) void*)l, 16, 0, 0);
}

// ---- weight pack: [co][ci][kh][kw] f32 -> [co][k] bf16, k=(kh*3+kw)*128+ci
__global__ void pack_weight(const float* __restrict__ w,
                            unsigned short* __restrict__ wp) {
    int idx = blockIdx.x * 256 + threadIdx.x;
    int co = idx / KSZ;
    int k  = idx - co * KSZ;
    int khkw = k >> 7;
    int ci = k & 127;
    wp[idx] = f2bf(w[(co * CIN + ci) * 9 + khkw]);
}

// ---- x transform: NCHW f32 -> padded NHWC bf16 [32][58][58][128]
__global__ __launch_bounds__(256)
void xform(const float* __restrict__ x, unsigned short* __restrict__ xt) {
    const int nb = blockIdx.x;
    const int n  = nb / HP;
    const int hp = nb - n * HP;
    unsigned short* orow = xt + ((size_t)n * HP + hp) * (HP * CIN);
    const int t = threadIdx.x;

    if (hp == 0 || hp == HP - 1) {
        for (int i = t; i < (HP * CIN) / 8; i += 256)
            ((ushort8*)orow)[i] = (ushort8){0, 0, 0, 0, 0, 0, 0, 0};
        return;
    }
    const int h = hp - 1;
    __shared__ unsigned short T[CIN][HP];
    const int wl = t & 63, cg = t >> 6;
    for (int c0 = 0; c0 < CIN; c0 += 4) {
        int ci = c0 + cg;
        if (wl < HW_)
            T[ci][wl] = f2bf(x[(((size_t)n * CIN + ci) * HW_ + h) * HW_ + wl]);
    }
    __syncthreads();
    const int ci = t & 127, wo = t >> 7;
    for (int wp_ = wo; wp_ < HP; wp_ += 2) {
        unsigned short v = 0;
        if (wp_ >= 1 && wp_ <= HW_) v = T[ci][wp_ - 1];
        orow[wp_ * CIN + ci] = v;
    }
}

// ---- main conv: 256x256 tile, BK=64, 8 waves, 4 phases/K-tile, counted vmcnt
__global__ __launch_bounds__(512, 1)
void conv8(const unsigned short* __restrict__ xt,
           const unsigned short* __restrict__ wpk,
           float* __restrict__ out)
{
    // buf b: A at [b*65536, +32768), B at [b*65536+32768, +32768)
    __shared__ __align__(16) char lds[131072];

    const int tid  = threadIdx.x;
    const int lane = tid & 63;
    const int wid  = tid >> 6;

    int bid = blockIdx.x;
    bid = (bid & 7) * 49 + (bid >> 3);          // XCD swizzle, 392 = 8*49 bijective
    const int m0 = bid << 8;

    // ---- staging source byte offsets (pre-swizzled: col ^= (row&7)<<4) ----
    const uint32_t scb = (uint32_t)((((tid & 7) ^ ((tid >> 3) & 7)) << 4));
    uint32_t aoff[4], boff[4];
    #pragma unroll
    for (int q = 0; q < 4; ++q) {
        int r = q * 64 + (tid >> 3);
        int m = m0 + r;
        int n = m / IMGHW;
        int rem = m - n * IMGHW;
        int h = rem / HW_;
        int w = rem - h * HW_;
        aoff[q] = (uint32_t)(((n * HP + h) * HP + w) << 8) + scb;
        boff[q] = (uint32_t)(r * (KSZ * 2)) + scb;
    }

    // ---- fragment LDS byte offsets (swizzled reads) ----
    const int fr = lane & 15, fg = lane >> 4;
    const int fsw = (lane & 7) << 4;
    const int c0h = ((fg << 4)) ^ fsw;          // k-half 0
    const int c1h = (64 | (fg << 4)) ^ fsw;     // k-half 1
    const int wm0 = (wid >> 2) << 7;            // 0 / 128
    const int wn0 = (wid & 3) << 6;             // 0..192
    const int aB0 = (wm0 + fr) * 128 + c0h;
    const int aB1 = (wm0 + fr) * 128 + c1h;
    const int bB0 = 32768 + (wn0 + fr) * 128 + c0h;
    const int bB1 = 32768 + (wn0 + fr) * 128 + c1h;

    const char* xtc = (const char*)xt;
    const char* wpc = (const char*)wpk;

    f32x4 acc[8][4];
    #pragma unroll
    for (int i = 0; i < 8; ++i)
        #pragma unroll
        for (int j = 0; j < 4; ++j)
            acc[i][j] = (f32x4){0.f, 0.f, 0.f, 0.f};

    ushort8 areg[8], breg[4];

    auto STAGE = [&](int t, int q) {            // stage part q of K-tile t
        const int bufo = (t & 1) << 16;
        int tap = t >> 1;
        int kh = (tap * 11) >> 5;               // tap/3 for tap<9
        int kw = tap - kh * 3;
        uint32_t ta = aoff[q] + (uint32_t)(((kh * HP + kw) << 8) + ((t & 1) << 7));
        uint32_t tb = boff[q] + (uint32_t)(t << 7);
        char* base = &lds[bufo];
        gl2lds16(xtc + ta, base + (q << 13) + (tid << 4));
        gl2lds16(wpc + tb, base + 32768 + (q << 13) + (tid << 4));
    };

    #define LGKM0 do { asm volatile("s_waitcnt lgkmcnt(0)" ::: "memory"); \
                       __builtin_amdgcn_sched_barrier(0); } while (0)
    #define MMROW(mf) do { \
        acc[mf][0] = __builtin_amdgcn_mfma_f32_16x16x32_bf16( \
            __builtin_bit_cast(bf16x8, breg[0]), __builtin_bit_cast(bf16x8, areg[mf]), acc[mf][0], 0, 0, 0); \
        acc[mf][1] = __builtin_amdgcn_mfma_f32_16x16x32_bf16( \
            __builtin_bit_cast(bf16x8, breg[1]), __builtin_bit_cast(bf16x8, areg[mf]), acc[mf][1], 0, 0, 0); \
        acc[mf][2] = __builtin_amdgcn_mfma_f32_16x16x32_bf16( \
            __builtin_bit_cast(bf16x8, breg[2]), __builtin_bit_cast(bf16x8, areg[mf]), acc[mf][2], 0, 0, 0); \
        acc[mf][3] = __builtin_amdgcn_mfma_f32_16x16x32_bf16( \
            __builtin_bit_cast(bf16x8, breg[3]), __builtin_bit_cast(bf16x8, areg[mf]), acc[mf][3], 0, 0, 0); \
    } while (0)

    // ---- prologue: tile0 parts 0-3, tile1 part 0; counted gate ----
    STAGE(0, 0); STAGE(0, 1); STAGE(0, 2); STAGE(0, 3);
    STAGE(1, 0);
    asm volatile("s_waitcnt vmcnt(2)" ::: "memory");
    __builtin_amdgcn_s_barrier();

    for (int t = 0; t < NT; ++t) {
        const int bufo = (t & 1) << 16;
        const char* L = lds;

        // ===== P0: quadrant (m0-3, h0) =====
        breg[0] = *(const ushort8*)(L + bufo + bB0 + 0 * 2048);
        breg[1] = *(const ushort8*)(L + bufo + bB0 + 1 * 2048);
        breg[2] = *(const ushort8*)(L + bufo + bB0 + 2 * 2048);
        breg[3] = *(const ushort8*)(L + bufo + bB0 + 3 * 2048);
        areg[0] = *(const ushort8*)(L + bufo + aB0 + 0 * 2048);
        areg[1] = *(const ushort8*)(L + bufo + aB0 + 1 * 2048);
        areg[2] = *(const ushort8*)(L + bufo + aB0 + 2 * 2048);
        areg[3] = *(const ushort8*)(L + bufo + aB0 + 3 * 2048);
        if (t + 1 < NT) STAGE(t + 1, 1);
        __builtin_amdgcn_s_barrier();
        LGKM0;
        __builtin_amdgcn_s_setprio(1);
        MMROW(0); MMROW(1); MMROW(2); MMROW(3);
        __builtin_amdgcn_s_setprio(0);
        __builtin_amdgcn_s_barrier();

        // ===== P1: quadrant (m4-7, h0) =====
        areg[4] = *(const ushort8*)(L + bufo + aB0 + 4 * 2048);
        areg[5] = *(const ushort8*)(L + bufo + aB0 + 5 * 2048);
        areg[6] = *(const ushort8*)(L + bufo + aB0 + 6 * 2048);
        areg[7] = *(const ushort8*)(L + bufo + aB0 + 7 * 2048);
        if (t + 1 < NT) STAGE(t + 1, 2);
        __builtin_amdgcn_s_barrier();
        LGKM0;
        __builtin_amdgcn_s_setprio(1);
        MMROW(4); MMROW(5); MMROW(6); MMROW(7);
        __builtin_amdgcn_s_setprio(0);
        __builtin_amdgcn_s_barrier();

        // ===== P2: quadrant (m0-3, h1) =====
        breg[0] = *(const ushort8*)(L + bufo + bB1 + 0 * 2048);
        breg[1] = *(const ushort8*)(L + bufo + bB1 + 1 * 2048);
        breg[2] = *(const ushort8*)(L + bufo + bB1 + 2 * 2048);
        breg[3] = *(const ushort8*)(L + bufo + bB1 + 3 * 2048);
        areg[0] = *(const ushort8*)(L + bufo + aB1 + 0 * 2048);
        areg[1] = *(const ushort8*)(L + bufo + aB1 + 1 * 2048);
        areg[2] = *(const ushort8*)(L + bufo + aB1 + 2 * 2048);
        areg[3] = *(const ushort8*)(L + bufo + aB1 + 3 * 2048);
        if (t + 1 < NT) STAGE(t + 1, 3);
        __builtin_amdgcn_s_barrier();
        LGKM0;
        __builtin_amdgcn_s_setprio(1);
        MMROW(0); MMROW(1); MMROW(2); MMROW(3);
        __builtin_amdgcn_s_setprio(0);
        __builtin_amdgcn_s_barrier();

        // ===== P3: quadrant (m4-7, h1) =====
        areg[4] = *(const ushort8*)(L + bufo + aB1 + 4 * 2048);
        areg[5] = *(const ushort8*)(L + bufo + aB1 + 5 * 2048);
        areg[6] = *(const ushort8*)(L + bufo + aB1 + 6 * 2048);
        areg[7] = *(const ushort8*)(L + bufo + aB1 + 7 * 2048);
        if (t + 2 < NT) STAGE(t + 2, 0);
        __builtin_amdgcn_s_barrier();
        LGKM0;
        __builtin_amdgcn_s_setprio(1);
        MMROW(4); MMROW(5); MMROW(6); MMROW(7);
        __builtin_amdgcn_s_setprio(0);
        // gate tile t+1 readiness (counted; drain only at tail)
        if (t + 2 < NT)      asm volatile("s_waitcnt vmcnt(2)" ::: "memory");
        else if (t + 1 < NT) asm volatile("s_waitcnt vmcnt(0)" ::: "memory");
        __builtin_amdgcn_s_barrier();
    }

    // ---- epilogue: D row = co (nf,fg,q), col = m (mf,fr); lanes 0-15 contiguous in w
    const int mwave = m0 + wm0;
    const int co0 = wn0 + (fg << 2);
    #pragma unroll
    for (int mf = 0; mf < 8; ++mf) {
        int m = mwave + mf * 16 + fr;
        int n = m / IMGHW;
        int hwr = m - n * IMGHW;
        uint32_t basem = (uint32_t)(n * (CO_ * IMGHW) + hwr);
        #pragma unroll
        for (int nf = 0; nf < 4; ++nf)
            #pragma unroll
            for (int q = 0; q < 4; ++q)
                out[basem + (uint32_t)(co0 + nf * 16 + q) * IMGHW] = acc[mf][nf][q];
    }
    #undef LGKM0
    #undef MMROW
}

// ================= fallback (round-1 kernel, used if ws too small) ==========
#define BM    64
#define BK    32
#define NSTEP 36
#define LDSP  40

template<bool PACKED>
__global__ __launch_bounds__(256, 2)
void conv_fb(const float* __restrict__ x,
             const float* __restrict__ wraw,
             const unsigned short* __restrict__ wp,
             float* __restrict__ out)
{
    __shared__ __align__(16) unsigned short Al[2][BM][LDSP];
    __shared__ __align__(16) unsigned short Bl[2][CO_][LDSP];

    const int tid  = threadIdx.x;
    const int lane = tid & 63;
    const int wid  = tid >> 6;

    const int mb    = blockIdx.x;
    const int n_img = mb / 49;
    const int hw0   = (mb - n_img * 49) * BM;

    const int mm = lane;
    const int hw = hw0 + mm;
    const int h  = hw / HW_;
    const int w_ = hw - h * HW_;

    const int bco  = tid >> 2;
    const int bkkg = tid & 3;

    float   aPF[8];
    ushort8 bPF[4];

    auto loadA = [&](int step) {
        int khkw = step >> 2;
        int kh = khkw / 3, kw = khkw - (khkw / 3) * 3;
        int ci0 = (step & 3) * BK + wid * 8;
        int ih = h + kh - 1, iw = w_ + kw - 1;
        bool valid = ((unsigned)ih < (unsigned)HW_) && ((unsigned)iw < (unsigned)HW_);
        const float* px = x + (((size_t)(n_img * CIN + ci0) * HW_ + ih) * HW_ + iw);
        #pragma unroll
        for (int e = 0; e < 8; ++e)
            aPF[e] = valid ? px[e * IMGHW] : 0.f;
    };
    auto writeA = [&](int buf) {
        ushort8 v;
        #pragma unroll
        for (int e = 0; e < 8; ++e) v[e] = f2bf(aPF[e]);
        *(ushort8*)&Al[buf][mm][wid * 8] = v;
    };
    auto loadB = [&](int step) {
        if (PACKED) {
            int k0 = step * BK;
            #pragma unroll
            for (int r = 0; r < 4; ++r)
                bPF[r] = *(const ushort8*)&wp[(r * 64 + bco) * KSZ + k0 + bkkg * 8];
        } else {
            int khkw = step >> 2;
            int ci0 = (step & 3) * BK + bkkg * 8;
            #pragma unroll
            for (int r = 0; r < 4; ++r) {
                int co = r * 64 + bco;
                ushort8 v;
                #pragma unroll
                for (int e = 0; e < 8; ++e)
                    v[e] = f2bf(wraw[(co * CIN + ci0 + e) * 9 + khkw]);
                bPF[r] = v;
            }
        }
    };
    auto writeB = [&](int buf) {
        #pragma unroll
        for (int r = 0; r < 4; ++r)
            *(ushort8*)&Bl[buf][r * 64 + bco][bkkg * 8] = bPF[r];
    };

    f32x4 acc[4][4];
    #pragma unroll
    for (int i = 0; i < 4; ++i)
        #pragma unroll
        for (int j = 0; j < 4; ++j)
            acc[i][j] = (f32x4){0.f, 0.f, 0.f, 0.f};

    const int frow = lane & 15;
    const int fk   = (lane >> 4) * 8;

    loadA(0); loadB(0);
    writeA(0); writeB(0);
    __syncthreads();

    for (int s = 0; s < NSTEP; ++s) {
        const int cur = s & 1;
        if (s + 1 < NSTEP) { loadA(s + 1); loadB(s + 1); }

        ushort8 aF[4], bF[4];
        #pragma unroll
        for (int i = 0; i < 4; ++i)
            aF[i] = *(const ushort8*)&Bl[cur][wid * 64 + i * 16 + frow][fk];
        #pragma unroll
        for (int j = 0; j < 4; ++j)
            bF[j] = *(const ushort8*)&Al[cur][j * 16 + frow][fk];

        #pragma unroll
        for (int i = 0; i < 4; ++i)
            #pragma unroll
            for (int j = 0; j < 4; ++j)
                acc[i][j] = __builtin_amdgcn_mfma_f32_16x16x32_bf16(
                    __builtin_bit_cast(bf16x8, aF[i]),
                    __builtin_bit_cast(bf16x8, bF[j]),
                    acc[i][j], 0, 0, 0);

        if (s + 1 < NSTEP) { writeA(cur ^ 1); writeB(cur ^ 1); }
        __syncthreads();
    }

    float* ob = out + (size_t)n_img * (CO_ * IMGHW) + hw0;
    #pragma unroll
    for (int i = 0; i < 4; ++i) {
        int co0 = wid * 64 + i * 16 + (lane >> 4) * 4;
        #pragma unroll
        for (int j = 0; j < 4; ++j) {
            int mcol = j * 16 + (lane & 15);
            #pragma unroll
            for (int q = 0; q < 4; ++q)
                ob[(size_t)(co0 + q) * IMGHW + mcol] = acc[i][j][q];
        }
    }
}

extern "C" void kernel_launch(void* const* d_in, const int* in_sizes, int n_in,
                              void* d_out, int out_size, void* d_ws, size_t ws_size,
                              hipStream_t stream) {
    (void)in_sizes; (void)n_in; (void)out_size;
    const float* x  = (const float*)d_in[0];
    const float* wt = (const float*)d_in[1];
    float* out = (float*)d_out;

    if (ws_size >= WS_NEED) {
        unsigned short* xt  = (unsigned short*)d_ws;
        unsigned short* wpk = (unsigned short*)((char*)d_ws + XT_BYTES);
        xform<<<32 * HP, 256, 0, stream>>>(x, xt);
        pack_weight<<<(CO_ * KSZ) / 256, 256, 0, stream>>>(wt, wpk);
        conv8<<<392, 512, 0, stream>>>(xt, wpk, out);
    } else if (ws_size >= WP_BYTES) {
        unsigned short* wpk = (unsigned short*)d_ws;
        pack_weight<<<(CO_ * KSZ) / 256, 256, 0, stream>>>(wt, wpk);
        conv_fb<true><<<100352 / BM, 256, 0, stream>>>(x, wt, wpk, out);
    } else {
        conv_fb<false><<<100352 / BM, 256, 0, stream>>>(x, wt, nullptr, out);
    }
}

// Round 4
// 97.864 us; speedup vs baseline: 1.4228x; 1.0092x over previous
//
#include <hip/hip_runtime.h>
#include <stdint.h>

// Conv2d as implicit GEMM, bf16 MFMA, 224x256 tile, 4-phase counted-vmcnt schedule.
// x: [32,128,56,56] f32, w: [256,128,3,3] f32 -> out: [32,256,56,56] f32
// GEMM: M=100352, N=256, K=1152 (k=(kh*3+kw)*128+ci). 18 K-tiles of 64. Grid 448.

#define CIN   128
#define HW_   56
#define CO_   256
#define KSZ   1152
#define IMGHW 3136
#define HP    58
#define NT    18
#define BMM   224
#define ABUF  28672        // 224*64*2
#define BBUF  32768        // 256*64*2
#define BUFSZ 61440        // ABUF+BBUF
#define XT_BYTES ((size_t)32 * HP * HP * CIN * 2)   // 27,557,888
#define WP_BYTES ((size_t)CO_ * KSZ * 2)            // 589,824
#define WS_NEED  (XT_BYTES + WP_BYTES)

typedef __attribute__((ext_vector_type(8))) __bf16 bf16x8;
typedef __attribute__((ext_vector_type(4))) float f32x4;
typedef __attribute__((ext_vector_type(8))) unsigned short ushort8;

__device__ __forceinline__ unsigned short f2bf(float f) {
    unsigned int u = __float_as_uint(f);
    u += 0x7fffu + ((u >> 16) & 1u);   // RNE
    return (unsigned short)(u >> 16);
}

__device__ __forceinline__ void gl2lds16(const void* g, void* l) {
    __builtin_amdgcn_global_load_lds(
        (const __attribute__((address_space(1))) void*)g,
        (__attribute__((address_space(3))) void*)l, 16, 0, 0);
}

// ---- weight pack: [co][ci][kh][kw] f32 -> [co][k] bf16, k=(kh*3+kw)*128+ci
__global__ void pack_weight(const float* __restrict__ w,
                            unsigned short* __restrict__ wp) {
    int idx = blockIdx.x * 256 + threadIdx.x;
    int co = idx / KSZ;
    int k  = idx - co * KSZ;
    int khkw = k >> 7;
    int ci = k & 127;
    wp[idx] = f2bf(w[(co * CIN + ci) * 9 + khkw]);
}

// ---- x transform: NCHW f32 -> padded NHWC bf16 [32][58][58][128]
__global__ __launch_bounds__(256)
void xform(const float* __restrict__ x, unsigned short* __restrict__ xt) {
    const int nb = blockIdx.x;
    const int n  = nb / HP;
    const int hp = nb - n * HP;
    unsigned short* orow = xt + ((size_t)n * HP + hp) * (HP * CIN);
    const int t = threadIdx.x;

    if (hp == 0 || hp == HP - 1) {
        for (int i = t; i < (HP * CIN) / 8; i += 256)
            ((ushort8*)orow)[i] = (ushort8){0, 0, 0, 0, 0, 0, 0, 0};
        return;
    }
    const int h = hp - 1;
    __shared__ unsigned short T[CIN][HP];
    const int wl = t & 63, cg = t >> 6;
    for (int c0 = 0; c0 < CIN; c0 += 4) {
        int ci = c0 + cg;
        if (wl < HW_)
            T[ci][wl] = f2bf(x[(((size_t)n * CIN + ci) * HW_ + h) * HW_ + wl]);
    }
    __syncthreads();
    const int ci = t & 127, wo = t >> 7;
    for (int wp_ = wo; wp_ < HP; wp_ += 2) {
        unsigned short v = 0;
        if (wp_ >= 1 && wp_ <= HW_) v = T[ci][wp_ - 1];
        orow[wp_ * CIN + ci] = v;
    }
}

// ---- main conv: 224x256 tile, BK=64, 8 waves (2m x 4n), wave 112x64
__global__ __launch_bounds__(512, 1)
void conv8(const unsigned short* __restrict__ xt,
           const unsigned short* __restrict__ wpk,
           float* __restrict__ out)
{
    // buf b at b*61440: A [224][64]bf16 then B [256][64]bf16
    __shared__ __align__(16) char lds[2 * BUFSZ];   // 120 KiB

    const int tid  = threadIdx.x;
    const int lane = tid & 63;
    const int wid  = tid >> 6;

    int bid = blockIdx.x;
    bid = (bid & 7) * 56 + (bid >> 3);          // XCD swizzle, 448 = 8*56 bijective
    const int m0 = bid * BMM;

    // ---- staging source byte offsets (pre-swizzled: chunk ^= row&7) ----
    const uint32_t scb = (uint32_t)(((tid & 7) ^ ((tid >> 3) & 7)) << 4);
    uint32_t aoff[4], boff[4];
    #pragma unroll
    for (int q = 0; q < 4; ++q) {
        int r = 56 * q + (tid >> 3);            // A row (valid for tid<448)
        int m = m0 + r;
        int n = m / IMGHW;
        int rem = m - n * IMGHW;
        int h = rem / HW_;
        int w = rem - h * HW_;
        aoff[q] = (uint32_t)(((n * HP + h) * HP + w) << 8) + scb;
        boff[q] = (uint32_t)((64 * q + (tid >> 3)) * (KSZ * 2)) + scb;
    }

    // ---- fragment LDS byte offsets (swizzled reads) ----
    const int fr = lane & 15, fg = lane >> 4;
    const int fsw = (lane & 7) << 4;
    const int c0h = (fg << 4) ^ fsw;            // k-half 0: chunk fg
    const int c1h = ((4 | fg) << 4) ^ fsw;      // k-half 1: chunk 4+fg
    const int wm0 = (wid >> 2) * 112;           // 0 / 112
    const int wn0 = (wid & 3) << 6;             // 0..192
    const int aB0 = (wm0 + fr) * 128 + c0h;
    const int aB1 = (wm0 + fr) * 128 + c1h;
    const int bB0 = ABUF + (wn0 + fr) * 128 + c0h;
    const int bB1 = ABUF + (wn0 + fr) * 128 + c1h;

    const char* xtc = (const char*)xt;
    const char* wpc = (const char*)wpk;

    f32x4 acc[7][4];
    #pragma unroll
    for (int i = 0; i < 7; ++i)
        #pragma unroll
        for (int j = 0; j < 4; ++j)
            acc[i][j] = (f32x4){0.f, 0.f, 0.f, 0.f};

    ushort8 areg[7], breg[4];

    auto STAGE = [&](int t, int q) {            // stage part q of K-tile t into buf t&1
        const int bufo = (t & 1) * BUFSZ;
        int tap = t >> 1;
        int kh = (tap * 11) >> 5;               // tap/3 for tap<9
        int kw = tap - kh * 3;
        uint32_t ta = aoff[q] + (uint32_t)(((kh * HP + kw) << 8) + ((t & 1) << 7));
        uint32_t tb = boff[q] + (uint32_t)(t << 7);
        if (tid < 448)
            gl2lds16(xtc + ta, &lds[bufo + q * 7168 + tid * 16]);
        gl2lds16(wpc + tb, &lds[bufo + ABUF + q * 8192 + tid * 16]);
    };

    #define LGKM0 do { asm volatile("s_waitcnt lgkmcnt(0)" ::: "memory"); \
                       __builtin_amdgcn_sched_barrier(0); } while (0)
    #define MMROW(mf) do { \
        acc[mf][0] = __builtin_amdgcn_mfma_f32_16x16x32_bf16( \
            __builtin_bit_cast(bf16x8, breg[0]), __builtin_bit_cast(bf16x8, areg[mf]), acc[mf][0], 0, 0, 0); \
        acc[mf][1] = __builtin_amdgcn_mfma_f32_16x16x32_bf16( \
            __builtin_bit_cast(bf16x8, breg[1]), __builtin_bit_cast(bf16x8, areg[mf]), acc[mf][1], 0, 0, 0); \
        acc[mf][2] = __builtin_amdgcn_mfma_f32_16x16x32_bf16( \
            __builtin_bit_cast(bf16x8, breg[2]), __builtin_bit_cast(bf16x8, areg[mf]), acc[mf][2], 0, 0, 0); \
        acc[mf][3] = __builtin_amdgcn_mfma_f32_16x16x32_bf16( \
            __builtin_bit_cast(bf16x8, breg[3]), __builtin_bit_cast(bf16x8, areg[mf]), acc[mf][3], 0, 0, 0); \
    } while (0)

    // ---- prologue: tile0 fully staged, drain, go ----
    STAGE(0, 0); STAGE(0, 1); STAGE(0, 2); STAGE(0, 3);
    asm volatile("s_waitcnt vmcnt(0)" ::: "memory");
    __builtin_amdgcn_s_barrier();

    for (int t = 0; t < NT; ++t) {
        const int bufo = (t & 1) * BUFSZ;
        const char* L = lds;
        const bool pf = (t + 1 < NT);

        // ===== P0: (mf0-3, h0) ; stage t+1 parts 0,1 =====
        breg[0] = *(const ushort8*)(L + bufo + bB0 + 0 * 2048);
        breg[1] = *(const ushort8*)(L + bufo + bB0 + 1 * 2048);
        breg[2] = *(const ushort8*)(L + bufo + bB0 + 2 * 2048);
        breg[3] = *(const ushort8*)(L + bufo + bB0 + 3 * 2048);
        areg[0] = *(const ushort8*)(L + bufo + aB0 + 0 * 2048);
        areg[1] = *(const ushort8*)(L + bufo + aB0 + 1 * 2048);
        areg[2] = *(const ushort8*)(L + bufo + aB0 + 2 * 2048);
        areg[3] = *(const ushort8*)(L + bufo + aB0 + 3 * 2048);
        if (pf) { STAGE(t + 1, 0); STAGE(t + 1, 1); }
        __builtin_amdgcn_s_barrier();
        LGKM0;
        __builtin_amdgcn_s_setprio(1);
        MMROW(0); MMROW(1); MMROW(2); MMROW(3);
        __builtin_amdgcn_s_setprio(0);
        __builtin_amdgcn_s_barrier();

        // ===== P1: (mf4-6, h0) ; stage t+1 part 2 =====
        areg[4] = *(const ushort8*)(L + bufo + aB0 + 4 * 2048);
        areg[5] = *(const ushort8*)(L + bufo + aB0 + 5 * 2048);
        areg[6] = *(const ushort8*)(L + bufo + aB0 + 6 * 2048);
        if (pf) STAGE(t + 1, 2);
        __builtin_amdgcn_s_barrier();
        LGKM0;
        __builtin_amdgcn_s_setprio(1);
        MMROW(4); MMROW(5); MMROW(6);
        __builtin_amdgcn_s_setprio(0);
        __builtin_amdgcn_s_barrier();

        // ===== P2: (mf0-3, h1) ; stage t+1 part 3 =====
        breg[0] = *(const ushort8*)(L + bufo + bB1 + 0 * 2048);
        breg[1] = *(const ushort8*)(L + bufo + bB1 + 1 * 2048);
        breg[2] = *(const ushort8*)(L + bufo + bB1 + 2 * 2048);
        breg[3] = *(const ushort8*)(L + bufo + bB1 + 3 * 2048);
        areg[0] = *(const ushort8*)(L + bufo + aB1 + 0 * 2048);
        areg[1] = *(const ushort8*)(L + bufo + aB1 + 1 * 2048);
        areg[2] = *(const ushort8*)(L + bufo + aB1 + 2 * 2048);
        areg[3] = *(const ushort8*)(L + bufo + aB1 + 3 * 2048);
        if (pf) STAGE(t + 1, 3);
        __builtin_amdgcn_s_barrier();
        LGKM0;
        __builtin_amdgcn_s_setprio(1);
        MMROW(0); MMROW(1); MMROW(2); MMROW(3);
        __builtin_amdgcn_s_setprio(0);
        __builtin_amdgcn_s_barrier();

        // ===== P3: (mf4-6, h1) ; no stage; drain (youngest load >=1.5 phases old) =====
        areg[4] = *(const ushort8*)(L + bufo + aB1 + 4 * 2048);
        areg[5] = *(const ushort8*)(L + bufo + aB1 + 5 * 2048);
        areg[6] = *(const ushort8*)(L + bufo + aB1 + 6 * 2048);
        __builtin_amdgcn_s_barrier();
        LGKM0;
        __builtin_amdgcn_s_setprio(1);
        MMROW(4); MMROW(5); MMROW(6);
        __builtin_amdgcn_s_setprio(0);
        if (pf) asm volatile("s_waitcnt vmcnt(0)" ::: "memory");
        __builtin_amdgcn_s_barrier();
    }

    // ---- epilogue: per-wave 16x16 LDS transpose -> dwordx4 stores ----
    // scratch: wave-private f32 scr[16][20] at lds[wid*1280] (in A-buf0; last tile used buf1)
    float* scr = (float*)&lds[wid * 1280];
    const int co_l = lane >> 2;
    const int mq4  = (lane & 3) * 4;
    #pragma unroll
    for (int mf = 0; mf < 7; ++mf) {
        int ml = m0 + wm0 + mf * 16 + mq4;      // 4-aligned, never crosses w-row (56%4==0)
        int n = ml / IMGHW;
        int rem = ml - n * IMGHW;
        float* op = out + (size_t)n * (CO_ * IMGHW) + rem;
        #pragma unroll
        for (int nf = 0; nf < 4; ++nf) {
            #pragma unroll
            for (int q = 0; q < 4; ++q)
                scr[(fg * 4 + q) * 20 + fr] = acc[mf][nf][q];
            f32x4 v = *(const f32x4*)&scr[co_l * 20 + mq4];
            int co = wn0 + nf * 16 + co_l;
            *(f32x4*)(op + (size_t)co * IMGHW) = v;
        }
    }
    #undef LGKM0
    #undef MMROW
}

// ================= fallback (round-1 kernel, used if ws too small) ==========
#define BM    64
#define BK    32
#define NSTEP 36
#define LDSP  40

template<bool PACKED>
__global__ __launch_bounds__(256, 2)
void conv_fb(const float* __restrict__ x,
             const float* __restrict__ wraw,
             const unsigned short* __restrict__ wp,
             float* __restrict__ out)
{
    __shared__ __align__(16) unsigned short Al[2][BM][LDSP];
    __shared__ __align__(16) unsigned short Bl[2][CO_][LDSP];

    const int tid  = threadIdx.x;
    const int lane = tid & 63;
    const int wid  = tid >> 6;

    const int mb    = blockIdx.x;
    const int n_img = mb / 49;
    const int hw0   = (mb - n_img * 49) * BM;

    const int mm = lane;
    const int hw = hw0 + mm;
    const int h  = hw / HW_;
    const int w_ = hw - h * HW_;

    const int bco  = tid >> 2;
    const int bkkg = tid & 3;

    float   aPF[8];
    ushort8 bPF[4];

    auto loadA = [&](int step) {
        int khkw = step >> 2;
        int kh = khkw / 3, kw = khkw - (khkw / 3) * 3;
        int ci0 = (step & 3) * BK + wid * 8;
        int ih = h + kh - 1, iw = w_ + kw - 1;
        bool valid = ((unsigned)ih < (unsigned)HW_) && ((unsigned)iw < (unsigned)HW_);
        const float* px = x + (((size_t)(n_img * CIN + ci0) * HW_ + ih) * HW_ + iw);
        #pragma unroll
        for (int e = 0; e < 8; ++e)
            aPF[e] = valid ? px[e * IMGHW] : 0.f;
    };
    auto writeA = [&](int buf) {
        ushort8 v;
        #pragma unroll
        for (int e = 0; e < 8; ++e) v[e] = f2bf(aPF[e]);
        *(ushort8*)&Al[buf][mm][wid * 8] = v;
    };
    auto loadB = [&](int step) {
        if (PACKED) {
            int k0 = step * BK;
            #pragma unroll
            for (int r = 0; r < 4; ++r)
                bPF[r] = *(const ushort8*)&wp[(r * 64 + bco) * KSZ + k0 + bkkg * 8];
        } else {
            int khkw = step >> 2;
            int ci0 = (step & 3) * BK + bkkg * 8;
            #pragma unroll
            for (int r = 0; r < 4; ++r) {
                int co = r * 64 + bco;
                ushort8 v;
                #pragma unroll
                for (int e = 0; e < 8; ++e)
                    v[e] = f2bf(wraw[(co * CIN + ci0 + e) * 9 + khkw]);
                bPF[r] = v;
            }
        }
    };
    auto writeB = [&](int buf) {
        #pragma unroll
        for (int r = 0; r < 4; ++r)
            *(ushort8*)&Bl[buf][r * 64 + bco][bkkg * 8] = bPF[r];
    };

    f32x4 acc[4][4];
    #pragma unroll
    for (int i = 0; i < 4; ++i)
        #pragma unroll
        for (int j = 0; j < 4; ++j)
            acc[i][j] = (f32x4){0.f, 0.f, 0.f, 0.f};

    const int frow = lane & 15;
    const int fk   = (lane >> 4) * 8;

    loadA(0); loadB(0);
    writeA(0); writeB(0);
    __syncthreads();

    for (int s = 0; s < NSTEP; ++s) {
        const int cur = s & 1;
        if (s + 1 < NSTEP) { loadA(s + 1); loadB(s + 1); }

        ushort8 aF[4], bF[4];
        #pragma unroll
        for (int i = 0; i < 4; ++i)
            aF[i] = *(const ushort8*)&Bl[cur][wid * 64 + i * 16 + frow][fk];
        #pragma unroll
        for (int j = 0; j < 4; ++j)
            bF[j] = *(const ushort8*)&Al[cur][j * 16 + frow][fk];

        #pragma unroll
        for (int i = 0; i < 4; ++i)
            #pragma unroll
            for (int j = 0; j < 4; ++j)
                acc[i][j] = __builtin_amdgcn_mfma_f32_16x16x32_bf16(
                    __builtin_bit_cast(bf16x8, aF[i]),
                    __builtin_bit_cast(bf16x8, bF[j]),
                    acc[i][j], 0, 0, 0);

        if (s + 1 < NSTEP) { writeA(cur ^ 1); writeB(cur ^ 1); }
        __syncthreads();
    }

    float* ob = out + (size_t)n_img * (CO_ * IMGHW) + hw0;
    #pragma unroll
    for (int i = 0; i < 4; ++i) {
        int co0 = wid * 64 + i * 16 + (lane >> 4) * 4;
        #pragma unroll
        for (int j = 0; j < 4; ++j) {
            int mcol = j * 16 + (lane & 15);
            #pragma unroll
            for (int q = 0; q < 4; ++q)
                ob[(size_t)(co0 + q) * IMGHW + mcol] = acc[i][j][q];
        }
    }
}

extern "C" void kernel_launch(void* const* d_in, const int* in_sizes, int n_in,
                              void* d_out, int out_size, void* d_ws, size_t ws_size,
                              hipStream_t stream) {
    (void)in_sizes; (void)n_in; (void)out_size;
    const float* x  = (const float*)d_in[0];
    const float* wt = (const float*)d_in[1];
    float* out = (float*)d_out;

    if (ws_size >= WS_NEED) {
        unsigned short* xt  = (unsigned short*)d_ws;
        unsigned short* wpk = (unsigned short*)((char*)d_ws + XT_BYTES);
        xform<<<32 * HP, 256, 0, stream>>>(x, xt);
        pack_weight<<<(CO_ * KSZ) / 256, 256, 0, stream>>>(wt, wpk);
        conv8<<<448, 512, 0, stream>>>(xt, wpk, out);
    } else if (ws_size >= WP_BYTES) {
        unsigned short* wpk = (unsigned short*)d_ws;
        pack_weight<<<(CO_ * KSZ) / 256, 256, 0, stream>>>(wt, wpk);
        conv_fb<true><<<100352 / BM, 256, 0, stream>>>(x, wt, wpk, out);
    } else {
        conv_fb<false><<<100352 / BM, 256, 0, stream>>>(x, wt, nullptr, out);
    }
}